// Round 11
// baseline (45.693 us; speedup 1.0000x reference)
//
#include <hip/hip_runtime.h>

// Volume rendering: R=65536 rays, N=128 sorted samples/ray. fp32 in/out.
// HARD-WON RULES (rounds 2-10):
//  (1) __shfl_* is broken for 64-lane semantics here (three bit-identical
//      failures; identical math via LDS passes) — ALL cross-lane via LDS.
//  (2) Input order IS dict order: r7 (detect+shuffles) failed bit-identical
//      to r3 (no-detect+shuffles) => detection always selected dict-order
//      pointers; r8-r10 pass with that selection. Detection removed.
//  (3) fp32 in, fp32 out, out = feat[R,3] then depth[R].
//
// r11: 2 rays per wave (lane l owns samples 2l,2l+1 of both rays) —
// doubles memory-level parallelism, halves barriers per ray; detection
// phase (2 barriers + 1KB reads/block) removed. 4 barriers per 8 rays.

#define R_RAYS 65536
#define N_SAMP 128
#define FAR_DELTA 1e10f

__global__ __launch_bounds__(256) void volrend_kernel(
    const float* __restrict__ dv,   // depth_values [R,N]
    const float* __restrict__ dn,   // density      [R,N]
    const float* __restrict__ ft,   // feature      [R,N,3]
    const float* __restrict__ sp,   // sample_points[R,N,3]
    float* __restrict__ out_feat,   // [R,3]
    float* __restrict__ out_depth)  // [R]
{
    __shared__ float  s_scan[4][2][64];   // per-wave, per-ray pair-sums
    __shared__ float  s_gsum[4][2][8];    // group totals (groups of 8)
    __shared__ float4 s_red [4][2][64];   // (fx,fy,fz,dp) partials
    __shared__ float4 s_red8[4][2][8];    // group partials

    const int w    = threadIdx.x >> 6;          // wave in block (0..3)
    const int lane = threadIdx.x & 63;
    const int g    = lane >> 3;                 // group 0..7
    const int gl   = lane & 7;                  // pos in group
    const int ray0 = (blockIdx.x << 3) + (w << 1);  // this wave: rays ray0, ray0+1

    // ---- issue ALL global loads for both rays up front (max MLP) ----
    float d0[2], d1[2], d2v[2], g0[2], g1[2];
    float f0[2], f1[2], f2[2], f3[2], f4[2], f5[2], p2[2], p5[2];
    size_t baser[2], b3r[2];
    #pragma unroll
    for (int r = 0; r < 2; ++r) {
        const size_t base = (size_t)(ray0 + r) * N_SAMP + (size_t)(lane * 2);
        const size_t b3   = base * 3;
        baser[r] = base; b3r[r] = b3;
        d0[r]  = dv[base];
        d1[r]  = dv[base + 1];
        d2v[r] = (lane == 63) ? 0.0f : dv[base + 2];
        g0[r]  = dn[base];
        g1[r]  = dn[base + 1];
        f0[r]  = ft[b3 + 0];
        f1[r]  = ft[b3 + 1];
        f2[r]  = ft[b3 + 2];
        f3[r]  = ft[b3 + 3];
        f4[r]  = ft[b3 + 4];
        f5[r]  = ft[b3 + 5];
        p2[r]  = sp[b3 + 2];
        p5[r]  = sp[b3 + 5];
    }

    // ---- sig_delta for both rays; write scan inputs; ONE barrier ----
    float s0[2], s1[2], lsum[2];
    #pragma unroll
    for (int r = 0; r < 2; ++r) {
        float delta0 = d1[r] - d0[r];
        float delta1 = (lane == 63) ? FAR_DELTA : (d2v[r] - d1[r]);
        s0[r] = -g0[r] * delta0;
        s1[r] = -g1[r] * delta1;
        lsum[r] = s0[r] + s1[r];
        s_scan[w][r][lane] = lsum[r];
    }
    __syncthreads();

    // ---- within-group exclusive prefix (broadcast reads) ----
    float excl_g[2] = {0.0f, 0.0f};
    #pragma unroll
    for (int r = 0; r < 2; ++r) {
        #pragma unroll
        for (int k = 0; k < 7; ++k) {
            float v = s_scan[w][r][(g << 3) + k];
            if (k < gl) excl_g[r] += v;
        }
        if (gl == 7) s_gsum[w][r][g] = excl_g[r] + lsum[r];
    }
    __syncthreads();

    // ---- group-level exclusive prefix + weights + partials ----
    #pragma unroll
    for (int r = 0; r < 2; ++r) {
        float gexcl = 0.0f;
        #pragma unroll
        for (int j = 0; j < 7; ++j) {
            float v = s_gsum[w][r][j];
            if (j < g) gexcl += v;
        }
        float excl0 = gexcl + excl_g[r];    // sum sig_delta[0..2l-1]
        float excl1 = excl0 + s0[r];        // sum sig_delta[0..2l]

        float w0 = __expf(excl0) * (1.0f - __expf(s0[r]));
        float w1 = __expf(excl1) * (1.0f - __expf(s1[r]));

        float fx = w0 * f0[r] + w1 * f3[r];
        float fy = w0 * f1[r] + w1 * f4[r];
        float fz = w0 * f2[r] + w1 * f5[r];
        float dp = g0[r] * p2[r] + g1[r] * p5[r];

        s_red[w][r][lane] = make_float4(fx, fy, fz, dp);
    }
    __syncthreads();

    // ---- group-of-8 reduction, both rays, shared barriers ----
    if (gl == 0) {
        #pragma unroll
        for (int r = 0; r < 2; ++r) {
            float4 acc = make_float4(0.f, 0.f, 0.f, 0.f);
            #pragma unroll
            for (int k = 0; k < 8; ++k) {
                int idx = (g << 3) + ((k + g) & 7);   // stagger banks
                float4 t = s_red[w][r][idx];
                acc.x += t.x; acc.y += t.y; acc.z += t.z; acc.w += t.w;
            }
            s_red8[w][r][g] = acc;
        }
    }
    __syncthreads();

    if (lane == 0) {
        #pragma unroll
        for (int r = 0; r < 2; ++r) {
            float4 acc = s_red8[w][r][0];
            #pragma unroll
            for (int k = 1; k < 8; ++k) {
                float4 t = s_red8[w][r][k];
                acc.x += t.x; acc.y += t.y; acc.z += t.z; acc.w += t.w;
            }
            const int ray = ray0 + r;
            out_feat[(size_t)ray * 3 + 0] = acc.x;
            out_feat[(size_t)ray * 3 + 1] = acc.y;
            out_feat[(size_t)ray * 3 + 2] = acc.z;
            out_depth[ray] = acc.w * (1.0f / N_SAMP);
        }
    }
}

extern "C" void kernel_launch(void* const* d_in, const int* in_sizes, int n_in,
                              void* d_out, int out_size, void* d_ws, size_t ws_size,
                              hipStream_t stream) {
    const float* depth_values  = (const float*)d_in[0];
    const float* density       = (const float*)d_in[1];
    const float* feature       = (const float*)d_in[2];
    const float* sample_points = (const float*)d_in[3];

    float* out_feat  = (float*)d_out;                       // [R,3] first
    float* out_depth = (float*)d_out + (size_t)R_RAYS * 3;  // [R] after

    dim3 grid(R_RAYS / 8);   // 8 rays per 256-thread block (2 per wave)
    volrend_kernel<<<grid, 256, 0, stream>>>(
        depth_values, density, feature, sample_points, out_feat, out_depth);
}